// Round 7
// baseline (3598.645 us; speedup 1.0000x reference)
//
#include <hip/hip_runtime.h>
#include <cstdint>
#include <cstddef>

// Problem constants
#define B_SZ 512
#define S_SZ 120
#define D_SZ 216
#define H_SZ 1024
#define NG   4096     // 4*H
#define DP   256      // D padded to multiple of BK
#define KENC 1280     // DP + H
#define TMAX 24

// GEMM tile config
#define BM 64
#define BN 128
#define BK 64
#define NBUF 6        // lstm_chain staging buffers (6-slice window, k-split pairs)

using bf16_t = __bf16;
using bf16x8 = __attribute__((ext_vector_type(8))) __bf16;
using f32x4  = __attribute__((ext_vector_type(4))) float;

__device__ __forceinline__ void gload16(const void* g, void* l) {
  __builtin_amdgcn_global_load_lds(
      (const __attribute__((address_space(1))) void*)g,
      (__attribute__((address_space(3))) void*)l, 16, 0, 0);
}

__device__ __forceinline__ float fsigmoid(float x) {
  x = fminf(fmaxf(x, -30.f), 30.f);
  return 1.f / (1.f + __expf(-x));
}
__device__ __forceinline__ float ftanh(float x) {
  x = fminf(fmaxf(x, -15.f), 15.f);
  float e = __expf(2.f * x);
  return (e - 1.f) / (e + 1.f);
}

#define BUFB 24576

// lstm_chain LDS: SIX staging buffers (A 64x64 bf16 = 8KB + B 128x64 bf16 =
// 16KB each) = 144KB. The gate/exchange region (64 x 132 f32 = 33KB) ALIASES
// the two stage buffers that are provably free at step end.
struct __align__(16) SmemChain {
  bf16_t stage[NBUF][(BM + BN) * BK];  // 147456 B < 160 KiB
};

// gemm_step LDS (original baseline layout, union: 73728 B)
struct __align__(16) SmemG {
  union {
    bf16_t stage[3][(BM + BN) * BK];
    float gate[BM * 129];
  };
};

// ---------------------------------------------------------------------------
// Persistent kernel v7: all 144 LSTM steps, ONE cooperative launch, 256 WGs
// of 512 threads (8 waves = 2/SIMD). K-split wave layout: 2 k-groups x
// 2x2 tile-waves of 32x64, acc[2][4]; one wait+barrier per slice PAIR.
//
// COHERENCE PROTOCOL v2 (the MALL-amplification fix):
//   release: h stores sc0|sc1 (write-through to MALL), per-wave vmcnt(0)
//            drain, __syncthreads, flag store sc0|sc1 (flag>=s+1 => h of
//            step s is MALL-visible).
//   acquire: once-per-step panel spin (32 flags, one vector load, bypass)
//            followed by ONE agent-scope acquire load -> compiler emits the
//            L1/L2 invalidate (buffer_inv sc1). All h loads afterwards are
//            PLAIN CACHED: per-XCD L2 absorbs the 32x panel-consumer reuse
//            (h MALL traffic 32MB/step -> ~8MB/step; L2 serves the rest).
//   Ordering: the spin's vmcnt(0) drains all pre-invalidate staged loads
//   into LDS; every h load of step s+1 executes after the invalidate; h
//   buffers alternate so the staleness window is one step, and every step
//   boundary invalidates.
// ---------------------------------------------------------------------------
__global__ __launch_bounds__(512, 1) void lstm_chain(
    const bf16_t* __restrict__ srcbf,
    const bf16_t* __restrict__ Wcat,
    const bf16_t* __restrict__ Wdec,
    const float* __restrict__ biasE,
    const float* __restrict__ biasD,
    bf16_t* __restrict__ hA,
    bf16_t* __restrict__ hB,
    bf16_t* __restrict__ Hs,
    unsigned* __restrict__ flags)
{
  __shared__ SmemChain sm;
  const int t    = threadIdx.x;
  const int bid  = blockIdx.x;
  const int n0   = (bid & 31) * BN;   // x-fastest: W panels stay L2-resident
  const int m0   = (bid >> 5) * BM;
  const int lane = t & 63;
  const int wv   = t >> 6;            // 0..7
  const int kg   = wv & 1;            // k-group (0: even slices, 1: odd)
  const int wt   = wv >> 1;           // 0..3 tile wave
  const int tm   = wt >> 1;           // 0..1 row block (32 rows)
  const int tn   = wt & 1;            // 0..1 col block (64 cols)
  const int fr   = lane & 15;
  const int fq   = lane >> 4;

  char* ldsbase = (char*)&sm.stage[0][0];

  // ---- staging geometry (uniform: each wave = 1 A-chunk + 2 W-chunks) ----
  const int sgrp = lane >> 3;                        // 0..7 row in group
  const int sw8  = (((lane & 7) ^ sgrp) & 7) * 8;    // swizzled col (elems)
  const int aRowOff = 8 * wv + sgrp;                 // A rows 8w..8w+7
  const int wRowOff = 16 * wv + sgrp;                // W rows 16w..16w+15

  // ---- fragment read offsets (swizzle-aware, conflict-free) ----
  const int swz   = fr & 7;
  const int co0   = ((fq) ^ swz) * 16;
  const int co1   = ((4 + fq) ^ swz) * 16;
  const int arow0 = (tm * 32 + fr) * 128;
  const int arow1 = (tm * 32 + 16 + fr) * 128;
  const int brow  = 8192 + (tn * 64 + fr) * 128;
  const int u0    = n0 >> 2;

  const int panel = m0 >> 6;
  unsigned* flg = flags + panel * 32;     // this panel's 32 producer flags
  unsigned* myf = flg + (n0 >> 7);        // our own flag (BN=128)
  const unsigned* myFlagAddr = flg + (lane & 31);

  // stage one k-slice: 1 A gload + 2 W gloads per wave (3 vmcnt events).
  // All loads PLAIN CACHED (h coherence via per-step acquire invalidate).
  auto stageSlice = [&](const bf16_t* Ab, int sA, int ka,
                        const bf16_t* Wb, int sW2, int kw, int buf) {
    char* lb = ldsbase + buf * BUFB;
    const bf16_t* ap = Ab + (size_t)(m0 + aRowOff) * sA + sw8 + ka;
    gload16(ap, lb + wv * 1024);
    const bf16_t* wp = Wb + (size_t)(n0 + wRowOff) * sW2 + sw8 + kw;
    gload16(wp, lb + 8192 + wv * 2048);
    gload16(wp + (size_t)8 * sW2, lb + 8192 + wv * 2048 + 1024);
  };

  f32x4 acc[2][4];

  // 32x64 wave tile: per kk reads 2 A-frags + 4 B-frags, 8 MFMA (16/slice).
  auto compute = [&](int bf) {
    const char* Lb = ldsbase + bf * BUFB;
#pragma unroll
    for (int kk = 0; kk < 2; ++kk) {
      const int co = kk ? co1 : co0;
      bf16x8 av0 = *(const bf16x8*)(Lb + arow0 + co);
      bf16x8 av1 = *(const bf16x8*)(Lb + arow1 + co);
      bf16x8 bv[4];
#pragma unroll
      for (int j = 0; j < 4; ++j)
        bv[j] = *(const bf16x8*)(Lb + brow + j * 2048 + co);
#pragma unroll
      for (int j = 0; j < 4; ++j) {
        acc[0][j] = __builtin_amdgcn_mfma_f32_16x16x32_bf16(av0, bv[j], acc[0][j], 0, 0, 0);
        acc[1][j] = __builtin_amdgcn_mfma_f32_16x16x32_bf16(av1, bv[j], acc[1][j], 0, 0, 0);
      }
    }
  };

  // Once-per-step panel wait + ACQUIRE: spin on the 32 panel flags (bypass
  // loads), then one agent-scope acquire load -> L1/L2 invalidate so the
  // following plain h loads can't see stale lines. The spin's vmcnt(0) also
  // drains any loads issued just before it (their data is already in LDS).
  auto panelAcquire = [&](unsigned need) {
    for (;;) {
      unsigned v;
      asm volatile("global_load_dword %0, %1, off sc0 sc1\n\t"
                   "s_waitcnt vmcnt(0)"
                   : "=v"(v) : "v"(myFlagAddr) : "memory");
      if (__all((int)(v >= need))) break;
      __builtin_amdgcn_s_sleep(2);
    }
    (void)__hip_atomic_load(myFlagAddr, __ATOMIC_ACQUIRE,
                            __HIP_MEMORY_SCOPE_AGENT);
  };

  // ---- persistent per-thread state ----
  float c4[4] = {0.f, 0.f, 0.f, 0.f};   // LSTM c-state (WG-private mapping)
  float biasE4[4], biasD4[4];           // hoisted epilogue biases
#pragma unroll
  for (int j = 0; j < 4; ++j) {
    int col = n0 + tn * 64 + j * 16 + fr;
    biasE4[j] = biasE[col];
    biasD4[j] = biasD[col];
  }

  const bf16_t* hprev = hA;
  int b0 = 0;   // rolling buffer base: slice j of current step -> buf (b0+j)%6

  // ---- prologue: stage step-0 slices 0..3 (all src/Wcat) into bufs 0..3 ----
  stageSlice(srcbf, DP, 0,      Wcat, KENC, 0,      0);
  stageSlice(srcbf, DP, BK,     Wcat, KENC, BK,     1);
  stageSlice(srcbf, DP, 2 * BK, Wcat, KENC, 2 * BK, 2);
  stageSlice(srcbf, DP, 3 * BK, Wcat, KENC, 3 * BK, 3);

#pragma clang loop unroll(disable)
  for (int s = 0; s < 144; ++s) {
    const bool enc = (s <= 120);
    const int n1 = enc ? (DP / BK) : 0;
    const bf16_t* Wb  = enc ? Wcat : Wdec;
    const int     sWb = enc ? KENC : H_SZ;
    bf16_t* hnext = (s < 120) ? ((s & 1) ? hA : hB)
                              : (Hs + (size_t)(s - 120) * B_SZ * H_SZ);
    const int nTot   = n1 + H_SZ / BK;      // 20 enc-structured, 16 dec
    const int npairs = nTot >> 1;           // 10 / 8

    float bias4[4];
#pragma unroll
    for (int j = 0; j < 4; ++j) bias4[j] = enc ? biasE4[j] : biasD4[j];

#pragma unroll
    for (int i = 0; i < 2; ++i)
#pragma unroll
      for (int j = 0; j < 4; ++j) acc[i][j] = (f32x4){0.f, 0.f, 0.f, 0.f};

    // my compute buffer (slice 2p+kg) and the stage cursor (slice 4)
    int cbm = b0 + kg;          if (cbm >= NBUF) cbm -= NBUF;
    int sb  = b0 + 4;           if (sb  >= NBUF) sb  -= NBUF;

    // ---- K-loop over slice PAIRS: one wait + one barrier per pair ----
    for (int p = 0; p < npairs; ++p) {
      if (p < npairs - 1) {
        if (kg == 0) asm volatile("s_waitcnt vmcnt(9)" ::: "memory");
        else         asm volatile("s_waitcnt vmcnt(6)" ::: "memory");
      } else {
        if (kg == 0) asm volatile("s_waitcnt vmcnt(3)" ::: "memory");
        else         asm volatile("s_waitcnt vmcnt(0)" ::: "memory");
      }
      __builtin_amdgcn_s_barrier();

      const int js = 2 * p + 4;            // stage targets: js, js+1
      if (js < nTot) {
        // in-loop slices are ALWAYS h-sourced (src slices 0..3 staged at
        // step boundaries): A offset (js-n1)*BK into hprev, plain cached.
        stageSlice(hprev, H_SZ, (js - n1) * BK, Wb, sWb, js * BK, sb);
        int sb2 = sb + 1; if (sb2 >= NBUF) sb2 -= NBUF;
        stageSlice(hprev, H_SZ, (js + 1 - n1) * BK, Wb, sWb, (js + 1) * BK, sb2);
        sb = sb2 + 1; if (sb >= NBUF) sb -= NBUF;
      }

      compute(cbm);
      cbm += 2; if (cbm >= NBUF) cbm -= NBUF;
    }

    // ---- epilogue: cross-group sum + LSTM cell ----
    const int gbuf = (b0 + nTot + 4) % NBUF;
    float* gate = (float*)(ldsbase + gbuf * BUFB);
    __syncthreads();

    if (kg == 0) {
#pragma unroll
      for (int i = 0; i < 2; ++i)
#pragma unroll
        for (int j = 0; j < 4; ++j)
#pragma unroll
          for (int v = 0; v < 4; ++v) {
            int row = tm * 32 + i * 16 + fq * 4 + v;
            int col = tn * 64 + j * 16 + fr;
            gate[row * 132 + col] = acc[i][j][v] + bias4[j];
          }
    }
    __syncthreads();
    if (kg == 1) {
#pragma unroll
      for (int i = 0; i < 2; ++i)
#pragma unroll
        for (int j = 0; j < 4; ++j)
#pragma unroll
          for (int v = 0; v < 4; ++v) {
            int row = tm * 32 + i * 16 + fq * 4 + v;
            int col = tn * 64 + j * 16 + fr;
            gate[row * 132 + col] += acc[i][j][v];
          }
    }
    __syncthreads();

#pragma unroll
    for (int itc = 0; itc < 4; ++itc) {
      int ci  = itc * 512 + t;
      int brw = ci >> 5;   // 0..63 local batch row
      int ju  = ci & 31;   // 0..31 local unit
      f32x4 g = *(const f32x4*)&gate[brw * 132 + ju * 4];  // conflict-free
      float iv = fsigmoid(g[0]);
      float fv = fsigmoid(g[1]);
      float gv = ftanh(g[2]);
      float ov = fsigmoid(g[3]);
      float cn = fv * c4[itc] + iv * gv;     // c-state in registers
      c4[itc] = cn;
      bf16_t hb = (bf16_t)(ov * ftanh(cn));
      uint32_t hv32 = (uint32_t)__builtin_bit_cast(uint16_t, hb);
      size_t cix = (size_t)(m0 + brw) * H_SZ + (u0 + ju);
      asm volatile("global_store_short %0, %1, off sc0 sc1"
                   :: "v"((uint16_t*)&hnext[cix]), "v"(hv32) : "memory");
    }
    // release: per-wave store drain, barrier, publish flag (sc0|sc1).
    asm volatile("s_waitcnt vmcnt(0)" ::: "memory");
    __syncthreads();
    if (t == 0) {
      unsigned fv2 = (unsigned)(s + 1);
      asm volatile("global_store_dword %0, %1, off sc0 sc1"
                   :: "v"(myf), "v"(fv2) : "memory");
    }

    // ---- post-step: stage next step's slices 0..3 + panel acquire ----
    int nb0 = b0 + (nTot - ((nTot / NBUF) * NBUF));  // (b0 + nTot) mod 6
    if (nb0 >= NBUF) nb0 -= NBUF;
    if (s < 143) {
      const bool nxtEnc = (s + 1 <= 120);
      if (nxtEnc) {
        // src+W slices: no h dependency -> stage first, acquire second (flag
        // RT overlaps the staged loads' L2 latency; spin leaves vmcnt=0).
        const bf16_t* nxtA = srcbf + (size_t)((s + 1 < 120) ? (s + 1) : 119) * B_SZ * DP;
        int b = nb0;
#pragma unroll
        for (int q = 0; q < 4; ++q) {
          stageSlice(nxtA, DP, q * BK, Wcat, KENC, q * BK, b);
          b = (b == NBUF - 1) ? 0 : b + 1;
        }
        panelAcquire((unsigned)(s + 1));
      } else {
        // h slices: acquire first, then stage plain-cached; completion
        // covered by next K-loop's vmcnt ladder.
        panelAcquire((unsigned)(s + 1));
        int b = nb0;
#pragma unroll
        for (int q = 0; q < 4; ++q) {
          stageSlice(hnext, H_SZ, q * BK, Wdec, H_SZ, q * BK, b);
          b = (b == NBUF - 1) ? 0 : b + 1;
        }
      }
    }

    b0 = nb0;
    hprev = hnext;
  }
}

// ---------------------------------------------------------------------------
// Standalone GEMM (EPI=2 W_dec build, EPI=3 final projection) — baseline.
// ---------------------------------------------------------------------------
template <int EPI>
__global__ __launch_bounds__(256, 1) void gemm_step(
    const bf16_t* __restrict__ A1, int sA1, int n1,
    const bf16_t* __restrict__ A2, int sA2, int n2,
    const bf16_t* __restrict__ W, int sW,
    const float* __restrict__ bias,
    float* __restrict__ cbuf, bf16_t* __restrict__ hout,
    const float* __restrict__ addm, bf16_t* __restrict__ outb,
    float* __restrict__ outf)
{
  __shared__ SmemG sm;
  const int t    = threadIdx.x;
  const int m0   = blockIdx.y * BM;
  const int n0   = blockIdx.x * BN;
  const int lane = t & 63;
  const int wv   = t >> 6;
  const int wm   = wv >> 1, wn = wv & 1;
  const int fr   = lane & 15;
  const int fq   = lane >> 4;

  f32x4 acc[2][4] = {};

  float bias4[4];
  if (EPI == 1 || EPI == 3) {
#pragma unroll
    for (int j = 0; j < 4; ++j) {
      int col = n0 + wn * 64 + j * 16 + fr;
      bias4[j] = (EPI == 3 && col >= D_SZ) ? 0.f : bias[col];
    }
  }

  const int r0   = t >> 3;
  const int gcol = (((t & 7) ^ (r0 & 7)) * 8);
  char* ldsbase  = (char*)&sm.stage[0][0];
  const int wofs = wv * 1024;

  const bf16_t* pA1 = A1 ? A1 : A2;
  const bf16_t* pA2 = A2 ? A2 : A1;
  const bf16_t* a1p0 = pA1 + (size_t)(m0 + r0) * sA1 + gcol;
  const bf16_t* a1p1 = pA1 + (size_t)(m0 + r0 + 32) * sA1 + gcol;
  const bf16_t* a2p0 = pA2 + (size_t)(m0 + r0) * sA2 + gcol;
  const bf16_t* a2p1 = pA2 + (size_t)(m0 + r0 + 32) * sA2 + gcol;
  const bf16_t* wp0  = W + (size_t)(n0 + r0) * sW + gcol;
  const bf16_t* wp1  = W + (size_t)(n0 + r0 + 32) * sW + gcol;
  const bf16_t* wp2  = W + (size_t)(n0 + r0 + 64) * sW + gcol;
  const bf16_t* wp3  = W + (size_t)(n0 + r0 + 96) * sW + gcol;

  const int nTot = n1 + n2;

  auto stage = [&](int j, int bf) {
    char* Ab = ldsbase + bf * BUFB + wofs;
    char* Bb = ldsbase + bf * BUFB + 8192 + wofs;
    const int k = j * BK;
    const bf16_t *a0, *a1;
    if (j < n1) { a0 = a1p0 + k; a1 = a1p1 + k; }
    else { const int k2 = k - n1 * BK; a0 = a2p0 + k2; a1 = a2p1 + k2; }
    gload16(a0, Ab);
    gload16(a1, Ab + 4096);
    gload16(wp0 + k, Bb);
    gload16(wp1 + k, Bb + 4096);
    gload16(wp2 + k, Bb + 8192);
    gload16(wp3 + k, Bb + 12288);
  };

  const int swz  = fr & 7;
  const int co0  = ((fq) ^ swz) * 16;
  const int co1  = ((4 + fq) ^ swz) * 16;
  const int arow0 = (wm * 32 + fr) * 128;
  const int arow1 = (wm * 32 + 16 + fr) * 128;
  const int brow  = (wn * 64 + fr) * 128;

  auto compute = [&](int bf) {
    const char* Ab = ldsbase + bf * BUFB;
    const char* Bb = Ab + 8192;
#pragma unroll
    for (int kk = 0; kk < 2; ++kk) {
      const int co = kk ? co1 : co0;
      bf16x8 av0 = *(const bf16x8*)(Ab + arow0 + co);
      bf16x8 av1 = *(const bf16x8*)(Ab + arow1 + co);
      bf16x8 bv[4];
#pragma unroll
      for (int j = 0; j < 4; ++j)
        bv[j] = *(const bf16x8*)(Bb + brow + j * 2048 + co);
#pragma unroll
      for (int j = 0; j < 4; ++j) {
        acc[0][j] = __builtin_amdgcn_mfma_f32_16x16x32_bf16(av0, bv[j], acc[0][j], 0, 0, 0);
        acc[1][j] = __builtin_amdgcn_mfma_f32_16x16x32_bf16(av1, bv[j], acc[1][j], 0, 0, 0);
      }
    }
  };

  stage(0, 0);
  if (nTot > 1) stage(1, 1);
  int cb = 0, sb = 2;
  for (int it = 0; it < nTot; ++it) {
    if (it == nTot - 1) {
      asm volatile("s_waitcnt vmcnt(0)" ::: "memory");
    } else {
      asm volatile("s_waitcnt vmcnt(6)" ::: "memory");
    }
    __builtin_amdgcn_s_barrier();
    if (it + 2 < nTot) stage(it + 2, sb);
    sb = (sb == 2) ? 0 : sb + 1;
    compute(cb);
    cb = (cb == 2) ? 0 : cb + 1;
  }
  __syncthreads();

  if (EPI == 1) {
#pragma unroll
    for (int i = 0; i < 2; ++i)
#pragma unroll
      for (int j = 0; j < 4; ++j)
#pragma unroll
        for (int v = 0; v < 4; ++v) {
          int row = wm * 32 + i * 16 + fq * 4 + v;
          int col = wn * 64 + j * 16 + fr;
          sm.gate[row * 129 + col] = acc[i][j][v] + bias4[j];
        }
    __syncthreads();
    const int u0 = n0 >> 2;
#pragma unroll
    for (int itc = 0; itc < 8; ++itc) {
      int ci = itc * 256 + t;
      int brw = ci >> 5;
      int ju  = ci & 31;
      const float* gp = &sm.gate[brw * 129 + ju * 4];
      float iv = fsigmoid(gp[0]);
      float fv = fsigmoid(gp[1]);
      float gv = ftanh(gp[2]);
      float ov = fsigmoid(gp[3]);
      size_t cix = (size_t)(m0 + brw) * H_SZ + (u0 + ju);
      float cn = fv * cbuf[cix] + iv * gv;
      cbuf[cix] = cn;
      hout[cix] = (bf16_t)(ov * ftanh(cn));
    }
  }

  if (EPI == 2) {
#pragma unroll
    for (int i = 0; i < 2; ++i)
#pragma unroll
      for (int j = 0; j < 4; ++j)
#pragma unroll
        for (int v = 0; v < 4; ++v) {
          int gr = m0 + wm * 32 + i * 16 + fq * 4 + v;
          int gc = n0 + wn * 64 + j * 16 + fr;
          int orig = (gr & 3) * H_SZ + (gr >> 2);
          float val = acc[i][j][v] + addm[(size_t)orig * H_SZ + gc];
          outb[(size_t)gr * H_SZ + gc] = (bf16_t)val;
        }
  }

  if (EPI == 3) {
#pragma unroll
    for (int i = 0; i < 2; ++i)
#pragma unroll
      for (int j = 0; j < 4; ++j)
#pragma unroll
        for (int v = 0; v < 4; ++v) {
          int m = m0 + wm * 32 + i * 16 + fq * 4 + v;
          int n = n0 + wn * 64 + j * 16 + fr;
          if (n < D_SZ) {
            int ts = m >> 9;
            int bb = m & 511;
            outf[((size_t)bb * TMAX + ts) * D_SZ + n] = acc[i][j][v] + bias4[j];
          }
        }
  }
}

// src (B,S,D) fp32 -> srcbf (S,B,DP) bf16, zero-padded d>=216
__global__ void k_convert_src(const float* __restrict__ src, bf16_t* __restrict__ dst) {
  int idx = blockIdx.x * 256 + threadIdx.x;
  int total = S_SZ * B_SZ * DP;
  if (idx >= total) return;
  int d = idx % DP;
  int r = idx / DP;
  int b = r % B_SZ;
  int tt = r / B_SZ;
  float v = (d < D_SZ) ? src[((size_t)b * S_SZ + tt) * D_SZ + d] : 0.f;
  dst[idx] = (bf16_t)v;
}

__global__ void k_build_wcat(const float* __restrict__ Wih, const float* __restrict__ Whh,
                             bf16_t* __restrict__ Wcat) {
  int idx = blockIdx.x * 256 + threadIdx.x;
  if (idx >= NG * KENC) return;
  int k = idx % KENC;
  int r = idx / KENC;
  int o = (r & 3) * H_SZ + (r >> 2);
  float v;
  if (k < D_SZ)      v = Wih[(size_t)o * D_SZ + k];
  else if (k < DP)   v = 0.f;
  else               v = Whh[(size_t)o * H_SZ + (k - DP)];
  Wcat[idx] = (bf16_t)v;
}

__global__ void k_build_wout(const float* __restrict__ Wout, bf16_t* __restrict__ WoutB,
                             bf16_t* __restrict__ WoutT) {
  int idx = blockIdx.x * 256 + threadIdx.x;
  if (idx < 256 * H_SZ) {
    int h = idx % H_SZ, d = idx / H_SZ;
    WoutB[idx] = (bf16_t)((d < D_SZ) ? Wout[(size_t)d * H_SZ + h] : 0.f);
  }
  if (idx < H_SZ * DP) {
    int d = idx % DP, h = idx / DP;
    WoutT[idx] = (bf16_t)((d < D_SZ) ? Wout[(size_t)d * H_SZ + h] : 0.f);
  }
}

__global__ void k_build_bias(const float* __restrict__ bih, const float* __restrict__ bhh,
                             const float* __restrict__ Wih, const float* __restrict__ bout,
                             float* __restrict__ biasE, float* __restrict__ biasD) {
  int r = blockIdx.x * 256 + threadIdx.x;
  if (r >= NG) return;
  int o = (r & 3) * H_SZ + (r >> 2);
  float be = bih[o] + bhh[o];
  biasE[r] = be;
  float s = 0.f;
  const float* wr = Wih + (size_t)o * D_SZ;
  for (int d = 0; d < D_SZ; ++d) s += wr[d] * bout[d];
  biasD[r] = be + s;
}

extern "C" void kernel_launch(void* const* d_in, const int* in_sizes, int n_in,
                              void* d_out, int out_size, void* d_ws, size_t ws_size,
                              hipStream_t stream) {
  const float* src  = (const float*)d_in[0];
  const float* Wih  = (const float*)d_in[1];
  const float* Whh  = (const float*)d_in[2];
  const float* bih  = (const float*)d_in[3];
  const float* bhh  = (const float*)d_in[4];
  const float* Wout = (const float*)d_in[5];
  const float* bout = (const float*)d_in[6];

  char* ws = (char*)d_ws;
  size_t off = 0;
  auto alloc = [&](size_t bytes) {
    void* p = ws + off;
    off = (off + bytes + 255) & ~(size_t)255;
    return p;
  };
  bf16_t* srcbf = (bf16_t*)alloc((size_t)S_SZ * B_SZ * DP * 2);
  bf16_t* Wcat  = (bf16_t*)alloc((size_t)NG * KENC * 2);
  bf16_t* Wdec  = (bf16_t*)alloc((size_t)NG * H_SZ * 2);
  bf16_t* WoutB = (bf16_t*)alloc((size_t)256 * H_SZ * 2);
  bf16_t* WoutT = (bf16_t*)alloc((size_t)H_SZ * DP * 2);
  float*  biasE = (float*)alloc((size_t)NG * 4);
  float*  biasD = (float*)alloc((size_t)NG * 4);
  float*  cbuf  = (float*)alloc((size_t)B_SZ * H_SZ * 4);
  bf16_t* hP0   = (bf16_t*)alloc((size_t)B_SZ * H_SZ * 2);
  bf16_t* hP1   = (bf16_t*)alloc((size_t)B_SZ * H_SZ * 2);
  bf16_t* Hs    = (bf16_t*)alloc((size_t)TMAX * B_SZ * H_SZ * 2);
  unsigned* flags = (unsigned*)alloc(1024);

  hipMemsetAsync(hP0, 0, (size_t)B_SZ * H_SZ * 2, stream);
  hipMemsetAsync(flags, 0, 1024, stream);

  k_convert_src<<<(S_SZ * B_SZ * DP + 255) / 256, 256, 0, stream>>>(src, srcbf);
  k_build_wcat<<<(NG * KENC + 255) / 256, 256, 0, stream>>>(Wih, Whh, Wcat);
  k_build_wout<<<1024, 256, 0, stream>>>(Wout, WoutB, WoutT);
  k_build_bias<<<(NG + 255) / 256, 256, 0, stream>>>(bih, bhh, Wih, bout, biasE, biasD);

  // W_dec = W_hh(reordered) + W_ih(reordered) @ W_out   (M=4096, N=1024, K=256)
  gemm_step<2><<<dim3(H_SZ / BN, NG / BM), 256, 0, stream>>>(
      Wcat, KENC, DP / BK, nullptr, 0, 0, WoutT, DP,
      nullptr, nullptr, nullptr, Whh, Wdec, nullptr);

  // All 144 sequential steps: one persistent cooperative kernel, 512 threads.
  {
    const bf16_t* a_src = srcbf;
    const bf16_t* a_wc  = Wcat;
    const bf16_t* a_wd  = Wdec;
    const float*  a_bE  = biasE;
    const float*  a_bD  = biasD;
    bf16_t*       a_hA  = hP0;
    bf16_t*       a_hB  = hP1;
    bf16_t*       a_Hs  = Hs;
    unsigned*     a_fl  = flags;
    void* kargs[] = {&a_src, &a_wc, &a_wd, &a_bE, &a_bD,
                     &a_hA, &a_hB, &a_Hs, &a_fl};
    hipLaunchCooperativeKernel((void*)lstm_chain, dim3(256), dim3(512),
                               kargs, 0, stream);
  }

  // Final projection: Y(12288 x 216) = Hs(12288 x 1024) @ W_out^T + b_out
  gemm_step<3><<<dim3(2, (TMAX * B_SZ) / BM), 256, 0, stream>>>(
      nullptr, 0, 0, Hs, H_SZ, H_SZ / BK, WoutB, H_SZ,
      bout, nullptr, nullptr, nullptr, nullptr, (float*)d_out);
}